// Round 2
// baseline (461.483 us; speedup 1.0000x reference)
//
#include <hip/hip_runtime.h>
#include <math.h>

#define NN 20000
#define EE 320000
#define DD 256
#define ETOT (EE + NN)

__device__ __forceinline__ float gelu_exact(float x) {
    return 0.5f * x * (1.0f + erff(x * 0.70710678118654752f));
}

// ---------------- row-normalize: one wave per row ----------------
__global__ __launch_bounds__(256) void norm_k(const float* __restrict__ X, float* __restrict__ Y) {
    int wave = (blockIdx.x * 256 + threadIdx.x) >> 6;
    int lane = threadIdx.x & 63;
    const float4 v = *(const float4*)&X[wave * DD + lane * 4];
    float ss = v.x * v.x + v.y * v.y + v.z * v.z + v.w * v.w;
    for (int off = 32; off > 0; off >>= 1) ss += __shfl_down(ss, off, 64);
    ss = __shfl(ss, 0, 64);
    float n = sqrtf(ss);
    if (n == 0.0f) n = 1e-8f;
    float inv = 1.0f / n;
    float4 o; o.x = v.x * inv; o.y = v.y * inv; o.z = v.z * inv; o.w = v.w * inv;
    *(float4*)&Y[wave * DD + lane * 4] = o;
}

// ---------------- CSR build ----------------
__global__ void initdeg_k(int* deg) {
    int i = blockIdx.x * 256 + threadIdx.x;
    if (i < NN) deg[i] = 1;  // self loop
}

__global__ void count_k(const int* __restrict__ ei, int* deg) {
    int e = blockIdx.x * 256 + threadIdx.x;
    if (e < EE) atomicAdd(&deg[ei[EE + e]], 1);
}

#define SCAN_T 1024
#define ITEMS 20
__global__ __launch_bounds__(SCAN_T) void scan_k(const int* __restrict__ deg, int* __restrict__ offs,
                                                 int* __restrict__ cursor) {
    __shared__ int part[SCAN_T];
    int t = threadIdx.x;
    int base = t * ITEMS;
    int local[ITEMS];
    int sum = 0;
#pragma unroll
    for (int i = 0; i < ITEMS; ++i) {
        int idx = base + i;
        int v = (idx < NN) ? deg[idx] : 0;
        local[i] = v;
        sum += v;
    }
    part[t] = sum;
    __syncthreads();
    for (int s = 1; s < SCAN_T; s <<= 1) {
        int v = (t >= s) ? part[t - s] : 0;
        __syncthreads();
        part[t] += v;
        __syncthreads();
    }
    int run = (t == 0) ? 0 : part[t - 1];
#pragma unroll
    for (int i = 0; i < ITEMS; ++i) {
        int idx = base + i;
        if (idx < NN) {
            offs[idx] = run;
            cursor[idx] = run;
            run += local[i];
        }
    }
    if (t == SCAN_T - 1) offs[NN] = part[SCAN_T - 1];
}

__global__ void fill_k(const int* __restrict__ ei, int* cursor, int* __restrict__ csr) {
    int e = blockIdx.x * 256 + threadIdx.x;
    if (e < EE) {
        int s = ei[e];
        int d = ei[EE + e];
        int p = atomicAdd(&cursor[d], 1);
        csr[p] = s;
    } else if (e < EE + NN) {
        int i = e - EE;
        int p = atomicAdd(&cursor[i], 1);
        csr[p] = i;
    }
}

// ---------------- fp32 GEMM: H[N,256] = X[N,256] @ W[256,256] ----------------
__global__ __launch_bounds__(256) void gemm_k(const float* __restrict__ X, const float* __restrict__ W,
                                              float* __restrict__ H) {
    __shared__ float As[16][68];  // As[k][m]
    __shared__ float Ws[16][68];  // Ws[k][n]
    int t = threadIdx.x;
    int m0 = blockIdx.x * 64;
    int n0 = blockIdx.y * 64;
    int tx = t & 15, ty = t >> 4;

    float acc[4][4] = {{0.0f}};

    int lr = t >> 2;
    int lk = (t & 3) << 2;
    int wk = t >> 4;
    int wn = (t & 15) << 2;
    int arow = m0 + lr;
    bool avalid = arow < NN;

    for (int k0 = 0; k0 < DD; k0 += 16) {
        float4 av = avalid ? *(const float4*)&X[arow * DD + k0 + lk] : make_float4(0, 0, 0, 0);
        As[lk + 0][lr] = av.x;
        As[lk + 1][lr] = av.y;
        As[lk + 2][lr] = av.z;
        As[lk + 3][lr] = av.w;
        *(float4*)&Ws[wk][wn] = *(const float4*)&W[(k0 + wk) * DD + n0 + wn];
        __syncthreads();
#pragma unroll
        for (int k = 0; k < 16; ++k) {
            float4 a = *(const float4*)&As[k][ty << 2];
            float4 b = *(const float4*)&Ws[k][tx << 2];
            acc[0][0] += a.x * b.x; acc[0][1] += a.x * b.y; acc[0][2] += a.x * b.z; acc[0][3] += a.x * b.w;
            acc[1][0] += a.y * b.x; acc[1][1] += a.y * b.y; acc[1][2] += a.y * b.z; acc[1][3] += a.y * b.w;
            acc[2][0] += a.z * b.x; acc[2][1] += a.z * b.y; acc[2][2] += a.z * b.z; acc[2][3] += a.z * b.w;
            acc[3][0] += a.w * b.x; acc[3][1] += a.w * b.y; acc[3][2] += a.w * b.z; acc[3][3] += a.w * b.w;
        }
        __syncthreads();
    }
#pragma unroll
    for (int i = 0; i < 4; ++i) {
        int row = m0 + (ty << 2) + i;
        if (row < NN) {
            float4 o = make_float4(acc[i][0], acc[i][1], acc[i][2], acc[i][3]);
            *(float4*)&H[row * DD + n0 + (tx << 2)] = o;
        }
    }
}

// ---------------- s,d per node: one wave per row ----------------
__global__ __launch_bounds__(256) void sd_k(const float* __restrict__ H, const float* __restrict__ a_s,
                                            const float* __restrict__ a_d, float* __restrict__ sArr,
                                            float* __restrict__ dArr) {
    int wave = (blockIdx.x * 256 + threadIdx.x) >> 6;
    int lane = threadIdx.x & 63;
    const float4 h = *(const float4*)&H[wave * DD + lane * 4];
    const float4 vs = *(const float4*)&a_s[lane * 4];
    const float4 vd = *(const float4*)&a_d[lane * 4];
    float s = h.x * vs.x + h.y * vs.y + h.z * vs.z + h.w * vs.w;
    float d = h.x * vd.x + h.y * vd.y + h.z * vd.z + h.w * vd.w;
    for (int off = 32; off > 0; off >>= 1) {
        s += __shfl_down(s, off, 64);
        d += __shfl_down(d, off, 64);
    }
    if (lane == 0) {
        sArr[wave] = s;
        dArr[wave] = d;
    }
}

// ---------------- normalized edge weights: one wave per dst ----------------
__global__ __launch_bounds__(256) void wnorm_k(const float* __restrict__ sArr, const float* __restrict__ dArr,
                                               const int* __restrict__ offs, const int* __restrict__ csr,
                                               float* __restrict__ wn) {
    int dst = (blockIdx.x * 256 + threadIdx.x) >> 6;
    int lane = threadIdx.x & 63;
    int beg = offs[dst], end = offs[dst + 1];
    float dd = dArr[dst];
    float den = 0.0f;
    for (int base = beg; base < end; base += 64) {
        int idx = base + lane;
        float w = 0.0f;
        if (idx < end) {
            float a = sArr[csr[idx]] + dd;
            a = (a > 0.0f) ? a : 0.2f * a;
            w = expf(a);
            wn[idx] = w;
        }
        den += w;
    }
    for (int off = 32; off > 0; off >>= 1) den += __shfl_down(den, off, 64);
    den = __shfl(den, 0, 64);
    float inv = 1.0f / den;
    for (int base = beg; base < end; base += 64) {
        int idx = base + lane;
        if (idx < end) wn[idx] *= inv;
    }
}

// ---------------- strip SpMM + bias + gelu ----------------
// grid (625, 8): 32 dsts/block, 32-dim strip per blockIdx.y (2.5 MB -> L2-resident).
// 8 threads per dst, each holds a float4 of the strip.
__global__ __launch_bounds__(256) void spmm_k(const float* __restrict__ H, const float* __restrict__ wn,
                                              const int* __restrict__ offs, const int* __restrict__ csr,
                                              const float* __restrict__ bias, float* __restrict__ out) {
    int t = threadIdx.x;
    int sub = t & 7;
    int dst = blockIdx.x * 32 + (t >> 3);
    int dim = blockIdx.y * 32 + sub * 4;

    int beg = offs[dst], end = offs[dst + 1];
    const float* Hs = H + dim;

    float ax0 = 0, ay0 = 0, az0 = 0, aw0 = 0;
    float ax1 = 0, ay1 = 0, az1 = 0, aw1 = 0;

    int e = beg;
    for (; e + 1 < end; e += 2) {
        int s0 = csr[e], s1 = csr[e + 1];
        float w0 = wn[e], w1 = wn[e + 1];
        const float4 h0 = *(const float4*)&Hs[s0 * DD];
        const float4 h1 = *(const float4*)&Hs[s1 * DD];
        ax0 += w0 * h0.x; ay0 += w0 * h0.y; az0 += w0 * h0.z; aw0 += w0 * h0.w;
        ax1 += w1 * h1.x; ay1 += w1 * h1.y; az1 += w1 * h1.z; aw1 += w1 * h1.w;
    }
    if (e < end) {
        int s0 = csr[e];
        float w0 = wn[e];
        const float4 h0 = *(const float4*)&Hs[s0 * DD];
        ax0 += w0 * h0.x; ay0 += w0 * h0.y; az0 += w0 * h0.z; aw0 += w0 * h0.w;
    }

    const float4 b = *(const float4*)&bias[dim];
    float4 o;
    o.x = gelu_exact(ax0 + ax1 + b.x);
    o.y = gelu_exact(ay0 + ay1 + b.y);
    o.z = gelu_exact(az0 + az1 + b.z);
    o.w = gelu_exact(aw0 + aw1 + b.w);
    *(float4*)&out[dst * DD + dim] = o;
}

extern "C" void kernel_launch(void* const* d_in, const int* in_sizes, int n_in,
                              void* d_out, int out_size, void* d_ws, size_t ws_size,
                              hipStream_t stream) {
    const float* x  = (const float*)d_in[0];
    const int* ei   = (const int*)d_in[1];
    const float* W1 = (const float*)d_in[4];
    const float* as1 = (const float*)d_in[5];
    const float* ad1 = (const float*)d_in[6];
    const float* b1 = (const float*)d_in[7];
    const float* W2 = (const float*)d_in[8];
    const float* as2 = (const float*)d_in[9];
    const float* ad2 = (const float*)d_in[10];
    const float* b2 = (const float*)d_in[11];
    const float* W3 = (const float*)d_in[12];
    const float* as3 = (const float*)d_in[13];
    const float* ad3 = (const float*)d_in[14];
    const float* b3 = (const float*)d_in[15];

    float* A = (float*)d_ws;               // ping buffer [N,256]
    float* B = A + (size_t)NN * DD;        // h buffer    [N,256]
    float* sArr = B + (size_t)NN * DD;     // [N]
    float* dArr = sArr + NN;               // [N]
    int* offs = (int*)(dArr + NN);         // [N+1]
    int* cursor = offs + (NN + 1);         // [N]
    int* csr = cursor + NN;                // [ETOT]
    int* deg = csr + ETOT;                 // [N]
    float* wn = (float*)(deg + NN);        // [ETOT]

    // ---- build CSR (by dst) ----
    initdeg_k<<<(NN + 255) / 256, 256, 0, stream>>>(deg);
    count_k<<<(EE + 255) / 256, 256, 0, stream>>>(ei, deg);
    scan_k<<<1, SCAN_T, 0, stream>>>(deg, offs, cursor);
    fill_k<<<(ETOT + 255) / 256, 256, 0, stream>>>(ei, cursor, csr);

    // ---- normalize input rows ----
    norm_k<<<NN / 4, 256, 0, stream>>>(x, A);

    dim3 ggrid((NN + 63) / 64, DD / 64);
    dim3 sgrid(NN / 32, DD / 32);

    // layer 1: A -> B (h) -> A
    gemm_k<<<ggrid, 256, 0, stream>>>(A, W1, B);
    sd_k<<<NN / 4, 256, 0, stream>>>(B, as1, ad1, sArr, dArr);
    wnorm_k<<<NN / 4, 256, 0, stream>>>(sArr, dArr, offs, csr, wn);
    spmm_k<<<sgrid, 256, 0, stream>>>(B, wn, offs, csr, b1, A);

    // layer 2: A -> B -> A
    gemm_k<<<ggrid, 256, 0, stream>>>(A, W2, B);
    sd_k<<<NN / 4, 256, 0, stream>>>(B, as2, ad2, sArr, dArr);
    wnorm_k<<<NN / 4, 256, 0, stream>>>(sArr, dArr, offs, csr, wn);
    spmm_k<<<sgrid, 256, 0, stream>>>(B, wn, offs, csr, b2, A);

    // layer 3: A -> B -> d_out
    gemm_k<<<ggrid, 256, 0, stream>>>(A, W3, B);
    sd_k<<<NN / 4, 256, 0, stream>>>(B, as3, ad3, sArr, dArr);
    wnorm_k<<<NN / 4, 256, 0, stream>>>(sArr, dArr, offs, csr, wn);
    spmm_k<<<sgrid, 256, 0, stream>>>(B, wn, offs, csr, b3, (float*)d_out);
}

// Round 3
// 387.249 us; speedup vs baseline: 1.1917x; 1.1917x over previous
//
#include <hip/hip_runtime.h>
#include <math.h>

#define NN 20000
#define EE 320000
#define DD 256
#define ETOT (EE + NN)

typedef __attribute__((ext_vector_type(8))) short bf8;
typedef __attribute__((ext_vector_type(4))) float f32x4;

__device__ __forceinline__ float gelu_exact(float x) {
    return 0.5f * x * (1.0f + erff(x * 0.70710678118654752f));
}

// round-to-nearest-even f32 -> bf16 bits
__device__ __forceinline__ unsigned short f2bf(float v) {
    unsigned u = __float_as_uint(v);
    u += 0x7fffu + ((u >> 16) & 1u);
    return (unsigned short)(u >> 16);
}
__device__ __forceinline__ float bf2f(unsigned short h) {
    return __uint_as_float(((unsigned)h) << 16);
}
__device__ __forceinline__ void split2(float v, unsigned short& hi, unsigned short& lo) {
    hi = f2bf(v);
    lo = f2bf(v - bf2f(hi));
}

// ---------------- row-normalize + hi/lo split: one wave per row ----------------
__global__ __launch_bounds__(256) void norm_k(const float* __restrict__ X,
                                              unsigned short* __restrict__ Xh,
                                              unsigned short* __restrict__ Xl) {
    int wave = (blockIdx.x * 256 + threadIdx.x) >> 6;
    int lane = threadIdx.x & 63;
    const float4 v = *(const float4*)&X[wave * DD + lane * 4];
    float ss = v.x * v.x + v.y * v.y + v.z * v.z + v.w * v.w;
    for (int off = 32; off > 0; off >>= 1) ss += __shfl_down(ss, off, 64);
    ss = __shfl(ss, 0, 64);
    float n = sqrtf(ss);
    if (n == 0.0f) n = 1e-8f;
    float inv = 1.0f / n;
    float o[4] = {v.x * inv, v.y * inv, v.z * inv, v.w * inv};
    ushort4 hv, lv;
    split2(o[0], hv.x, lv.x);
    split2(o[1], hv.y, lv.y);
    split2(o[2], hv.z, lv.z);
    split2(o[3], hv.w, lv.w);
    *(ushort4*)&Xh[wave * DD + lane * 4] = hv;
    *(ushort4*)&Xl[wave * DD + lane * 4] = lv;
}

// ---------------- W transpose + hi/lo split: Wt[n][k] = W[k][n] ----------------
__global__ __launch_bounds__(256) void splitw_k(const float* __restrict__ W,
                                                unsigned short* __restrict__ Wht,
                                                unsigned short* __restrict__ Wlt) {
    __shared__ float tile[64][65];
    int t = threadIdx.x;
    int k0 = blockIdx.x * 64;
    int c0 = blockIdx.y * 64;
#pragma unroll
    for (int i = 0; i < 16; ++i) {
        int idx = t + i * 256;
        int r = idx >> 6, c = idx & 63;
        tile[r][c] = W[(k0 + r) * DD + c0 + c];
    }
    __syncthreads();
#pragma unroll
    for (int i = 0; i < 16; ++i) {
        int idx = t + i * 256;
        int r = idx >> 6, c = idx & 63;
        float v = tile[c][r];
        unsigned short hi, lo;
        split2(v, hi, lo);
        Wht[(c0 + r) * DD + k0 + c] = hi;
        Wlt[(c0 + r) * DD + k0 + c] = lo;
    }
}

// ---------------- CSR build ----------------
__global__ void initdeg_k(int* deg) {
    int i = blockIdx.x * 256 + threadIdx.x;
    if (i < NN) deg[i] = 1;
}

__global__ void count_k(const int* __restrict__ ei, int* deg) {
    int e = blockIdx.x * 256 + threadIdx.x;
    if (e < EE) atomicAdd(&deg[ei[EE + e]], 1);
}

#define SCAN_T 1024
#define ITEMS 20
__global__ __launch_bounds__(SCAN_T) void scan_k(const int* __restrict__ deg, int* __restrict__ offs,
                                                 int* __restrict__ cursor) {
    __shared__ int part[SCAN_T];
    int t = threadIdx.x;
    int base = t * ITEMS;
    int local[ITEMS];
    int sum = 0;
#pragma unroll
    for (int i = 0; i < ITEMS; ++i) {
        int idx = base + i;
        int v = (idx < NN) ? deg[idx] : 0;
        local[i] = v;
        sum += v;
    }
    part[t] = sum;
    __syncthreads();
    for (int s = 1; s < SCAN_T; s <<= 1) {
        int v = (t >= s) ? part[t - s] : 0;
        __syncthreads();
        part[t] += v;
        __syncthreads();
    }
    int run = (t == 0) ? 0 : part[t - 1];
#pragma unroll
    for (int i = 0; i < ITEMS; ++i) {
        int idx = base + i;
        if (idx < NN) {
            offs[idx] = run;
            cursor[idx] = run;
            run += local[i];
        }
    }
    if (t == SCAN_T - 1) offs[NN] = part[SCAN_T - 1];
}

__global__ void fill_k(const int* __restrict__ ei, int* cursor, int* __restrict__ csr) {
    int e = blockIdx.x * 256 + threadIdx.x;
    if (e < EE) {
        int s = ei[e];
        int d = ei[EE + e];
        int p = atomicAdd(&cursor[d], 1);
        csr[p] = s;
    } else if (e < EE + NN) {
        int i = e - EE;
        int p = atomicAdd(&cursor[i], 1);
        csr[p] = i;
    }
}

// ---------------- MFMA GEMM: H[N,256] = (Xh+Xl) @ (Wht+Wlt)^T, 3-product split ----
// 128x128 tile per 256-thread block, 4 waves; wave w does rows [w*32,w*32+32).
#define LDA 40  // padded k-stride (bf16 elems): 80B, 16B-aligned, conflict-free
__global__ __launch_bounds__(256) void gemm_mfma(const unsigned short* __restrict__ Xh,
                                                 const unsigned short* __restrict__ Xl,
                                                 const unsigned short* __restrict__ Bh,
                                                 const unsigned short* __restrict__ Bl,
                                                 float* __restrict__ H) {
    __shared__ unsigned short sAh[128 * LDA], sAl[128 * LDA], sBh[128 * LDA], sBl[128 * LDA];
    int t = threadIdx.x;
    int m0 = blockIdx.x * 128;
    int n0 = blockIdx.y * 128;
    int w = t >> 6, l = t & 63;

    f32x4 acc[2][8] = {};

    for (int k0 = 0; k0 < DD; k0 += 32) {
        __syncthreads();
#pragma unroll
        for (int i = 0; i < 2; ++i) {
            int c = t + i * 256;
            int row = c >> 2;
            int ko = (c & 3) * 8;
            int lofs = row * LDA + ko;
            bf8 zero = {0, 0, 0, 0, 0, 0, 0, 0};
            bf8 avh = zero, avl = zero;
            int arow = m0 + row;
            if (arow < NN) {
                avh = *(const bf8*)&Xh[arow * DD + k0 + ko];
                avl = *(const bf8*)&Xl[arow * DD + k0 + ko];
            }
            *(bf8*)&sAh[lofs] = avh;
            *(bf8*)&sAl[lofs] = avl;
            int brow = n0 + row;
            *(bf8*)&sBh[lofs] = *(const bf8*)&Bh[brow * DD + k0 + ko];
            *(bf8*)&sBl[lofs] = *(const bf8*)&Bl[brow * DD + k0 + ko];
        }
        __syncthreads();
        int rofs = l & 15;
        int kofs = (l >> 4) * 8;
        bf8 ah[2], al[2], bh[8], bl[8];
#pragma unroll
        for (int mt = 0; mt < 2; ++mt) {
            int r = (w * 2 + mt) * 16 + rofs;
            ah[mt] = *(const bf8*)&sAh[r * LDA + kofs];
            al[mt] = *(const bf8*)&sAl[r * LDA + kofs];
        }
#pragma unroll
        for (int nt = 0; nt < 8; ++nt) {
            int r = nt * 16 + rofs;
            bh[nt] = *(const bf8*)&sBh[r * LDA + kofs];
            bl[nt] = *(const bf8*)&sBl[r * LDA + kofs];
        }
#pragma unroll
        for (int mt = 0; mt < 2; ++mt)
#pragma unroll
            for (int nt = 0; nt < 8; ++nt) {
                acc[mt][nt] = __builtin_amdgcn_mfma_f32_16x16x32_bf16(ah[mt], bh[nt], acc[mt][nt], 0, 0, 0);
                acc[mt][nt] = __builtin_amdgcn_mfma_f32_16x16x32_bf16(ah[mt], bl[nt], acc[mt][nt], 0, 0, 0);
                acc[mt][nt] = __builtin_amdgcn_mfma_f32_16x16x32_bf16(al[mt], bh[nt], acc[mt][nt], 0, 0, 0);
            }
    }
    // C/D layout: col = lane&15, row = (lane>>4)*4 + reg  [m89]
    int col = l & 15;
#pragma unroll
    for (int mt = 0; mt < 2; ++mt) {
        int mrow0 = m0 + (w * 2 + mt) * 16 + (l >> 4) * 4;
#pragma unroll
        for (int nt = 0; nt < 8; ++nt) {
            int cc = n0 + nt * 16 + col;
#pragma unroll
            for (int r = 0; r < 4; ++r) {
                int row = mrow0 + r;
                if (row < NN) H[row * DD + cc] = acc[mt][nt][r];
            }
        }
    }
}

// ---------------- s,d per node: one wave per row ----------------
__global__ __launch_bounds__(256) void sd_k(const float* __restrict__ H, const float* __restrict__ a_s,
                                            const float* __restrict__ a_d, float* __restrict__ sArr,
                                            float* __restrict__ dArr) {
    int wave = (blockIdx.x * 256 + threadIdx.x) >> 6;
    int lane = threadIdx.x & 63;
    const float4 h = *(const float4*)&H[wave * DD + lane * 4];
    const float4 vs = *(const float4*)&a_s[lane * 4];
    const float4 vd = *(const float4*)&a_d[lane * 4];
    float s = h.x * vs.x + h.y * vs.y + h.z * vs.z + h.w * vs.w;
    float d = h.x * vd.x + h.y * vd.y + h.z * vd.z + h.w * vd.w;
    for (int off = 32; off > 0; off >>= 1) {
        s += __shfl_down(s, off, 64);
        d += __shfl_down(d, off, 64);
    }
    if (lane == 0) {
        sArr[wave] = s;
        dArr[wave] = d;
    }
}

// ---------------- normalized edge weights: one wave per dst ----------------
__global__ __launch_bounds__(256) void wnorm_k(const float* __restrict__ sArr, const float* __restrict__ dArr,
                                               const int* __restrict__ offs, const int* __restrict__ csr,
                                               float* __restrict__ wn) {
    int dst = (blockIdx.x * 256 + threadIdx.x) >> 6;
    int lane = threadIdx.x & 63;
    int beg = offs[dst], end = offs[dst + 1];
    float dd = dArr[dst];
    float den = 0.0f;
    for (int base = beg; base < end; base += 64) {
        int idx = base + lane;
        float w = 0.0f;
        if (idx < end) {
            float a = sArr[csr[idx]] + dd;
            a = (a > 0.0f) ? a : 0.2f * a;
            w = expf(a);
            wn[idx] = w;
        }
        den += w;
    }
    for (int off = 32; off > 0; off >>= 1) den += __shfl_down(den, off, 64);
    den = __shfl(den, 0, 64);
    float inv = 1.0f / den;
    for (int base = beg; base < end; base += 64) {
        int idx = base + lane;
        if (idx < end) wn[idx] *= inv;
    }
}

// ---------------- strip SpMM + bias + gelu + hi/lo split ----------------
// grid (8, 625): blockIdx.x = 32-dim strip. XCD = linear_id % 8 = blockIdx.x, so
// each XCD's L2 holds exactly one 2.5 MB H-strip for the whole dispatch.
__global__ __launch_bounds__(256) void spmm_k(const float* __restrict__ H, const float* __restrict__ wn,
                                              const int* __restrict__ offs, const int* __restrict__ csr,
                                              const float* __restrict__ bias,
                                              unsigned short* __restrict__ Oh,
                                              unsigned short* __restrict__ Ol,
                                              float* __restrict__ outf32) {
    int t = threadIdx.x;
    int sub = t & 7;
    int dst = blockIdx.y * 32 + (t >> 3);
    int dim = blockIdx.x * 32 + sub * 4;

    int beg = offs[dst], end = offs[dst + 1];
    const float* Hs = H + dim;

    float ax0 = 0, ay0 = 0, az0 = 0, aw0 = 0;
    float ax1 = 0, ay1 = 0, az1 = 0, aw1 = 0;

    int e = beg;
    for (; e + 1 < end; e += 2) {
        int s0 = csr[e], s1 = csr[e + 1];
        float w0 = wn[e], w1 = wn[e + 1];
        const float4 h0 = *(const float4*)&Hs[s0 * DD];
        const float4 h1 = *(const float4*)&Hs[s1 * DD];
        ax0 += w0 * h0.x; ay0 += w0 * h0.y; az0 += w0 * h0.z; aw0 += w0 * h0.w;
        ax1 += w1 * h1.x; ay1 += w1 * h1.y; az1 += w1 * h1.z; aw1 += w1 * h1.w;
    }
    if (e < end) {
        int s0 = csr[e];
        float w0 = wn[e];
        const float4 h0 = *(const float4*)&Hs[s0 * DD];
        ax0 += w0 * h0.x; ay0 += w0 * h0.y; az0 += w0 * h0.z; aw0 += w0 * h0.w;
    }

    const float4 b = *(const float4*)&bias[dim];
    float o0 = gelu_exact(ax0 + ax1 + b.x);
    float o1 = gelu_exact(ay0 + ay1 + b.y);
    float o2 = gelu_exact(az0 + az1 + b.z);
    float o3 = gelu_exact(aw0 + aw1 + b.w);

    ushort4 hv, lv;
    split2(o0, hv.x, lv.x);
    split2(o1, hv.y, lv.y);
    split2(o2, hv.z, lv.z);
    split2(o3, hv.w, lv.w);
    *(ushort4*)&Oh[dst * DD + dim] = hv;
    *(ushort4*)&Ol[dst * DD + dim] = lv;
    if (outf32) {
        float4 o = make_float4(o0, o1, o2, o3);
        *(float4*)&outf32[dst * DD + dim] = o;
    }
}

extern "C" void kernel_launch(void* const* d_in, const int* in_sizes, int n_in,
                              void* d_out, int out_size, void* d_ws, size_t ws_size,
                              hipStream_t stream) {
    const float* x  = (const float*)d_in[0];
    const int* ei   = (const int*)d_in[1];
    const float* W1 = (const float*)d_in[4];
    const float* as1 = (const float*)d_in[5];
    const float* ad1 = (const float*)d_in[6];
    const float* b1 = (const float*)d_in[7];
    const float* W2 = (const float*)d_in[8];
    const float* as2 = (const float*)d_in[9];
    const float* ad2 = (const float*)d_in[10];
    const float* b2 = (const float*)d_in[11];
    const float* W3 = (const float*)d_in[12];
    const float* as3 = (const float*)d_in[13];
    const float* ad3 = (const float*)d_in[14];
    const float* b3 = (const float*)d_in[15];

    float* H = (float*)d_ws;                              // [N,256] f32
    unsigned short* Xh = (unsigned short*)(H + (size_t)NN * DD);  // [N,256] bf16 bits
    unsigned short* Xl = Xh + (size_t)NN * DD;
    unsigned short* Wht1 = Xl + (size_t)NN * DD;          // 6 x [256,256]
    unsigned short* Wlt1 = Wht1 + DD * DD;
    unsigned short* Wht2 = Wlt1 + DD * DD;
    unsigned short* Wlt2 = Wht2 + DD * DD;
    unsigned short* Wht3 = Wlt2 + DD * DD;
    unsigned short* Wlt3 = Wht3 + DD * DD;
    float* sArr = (float*)(Wlt3 + DD * DD);               // [N]
    float* dArr = sArr + NN;                              // [N]
    int* offs = (int*)(dArr + NN);                        // [N+1]
    int* cursor = offs + (NN + 1);                        // [N]
    int* csr = cursor + NN;                               // [ETOT]
    int* deg = csr + ETOT;                                // [N]
    float* wn = (float*)(deg + NN);                       // [ETOT]

    // ---- build CSR (by dst) ----
    initdeg_k<<<(NN + 255) / 256, 256, 0, stream>>>(deg);
    count_k<<<(EE + 255) / 256, 256, 0, stream>>>(ei, deg);
    scan_k<<<1, SCAN_T, 0, stream>>>(deg, offs, cursor);
    fill_k<<<(ETOT + 255) / 256, 256, 0, stream>>>(ei, cursor, csr);

    // ---- W transpose+split (once each) ----
    dim3 wgrid(4, 4);
    splitw_k<<<wgrid, 256, 0, stream>>>(W1, Wht1, Wlt1);
    splitw_k<<<wgrid, 256, 0, stream>>>(W2, Wht2, Wlt2);
    splitw_k<<<wgrid, 256, 0, stream>>>(W3, Wht3, Wlt3);

    // ---- normalize input rows -> Xh/Xl ----
    norm_k<<<NN / 4, 256, 0, stream>>>(x, Xh, Xl);

    dim3 ggrid((NN + 127) / 128, DD / 128);
    dim3 sgrid(DD / 32, NN / 32);  // x = strip (XCD pin), y = dst group

    // layer 1
    gemm_mfma<<<ggrid, 256, 0, stream>>>(Xh, Xl, Wht1, Wlt1, H);
    sd_k<<<NN / 4, 256, 0, stream>>>(H, as1, ad1, sArr, dArr);
    wnorm_k<<<NN / 4, 256, 0, stream>>>(sArr, dArr, offs, csr, wn);
    spmm_k<<<sgrid, 256, 0, stream>>>(H, wn, offs, csr, b1, Xh, Xl, nullptr);

    // layer 2
    gemm_mfma<<<ggrid, 256, 0, stream>>>(Xh, Xl, Wht2, Wlt2, H);
    sd_k<<<NN / 4, 256, 0, stream>>>(H, as2, ad2, sArr, dArr);
    wnorm_k<<<NN / 4, 256, 0, stream>>>(sArr, dArr, offs, csr, wn);
    spmm_k<<<sgrid, 256, 0, stream>>>(H, wn, offs, csr, b2, Xh, Xl, nullptr);

    // layer 3
    gemm_mfma<<<ggrid, 256, 0, stream>>>(Xh, Xl, Wht3, Wlt3, H);
    sd_k<<<NN / 4, 256, 0, stream>>>(H, as3, ad3, sArr, dArr);
    wnorm_k<<<NN / 4, 256, 0, stream>>>(sArr, dArr, offs, csr, wn);
    spmm_k<<<sgrid, 256, 0, stream>>>(H, wn, offs, csr, b3, Xh, Xl, (float*)d_out);
}

// Round 4
// 371.014 us; speedup vs baseline: 1.2438x; 1.0438x over previous
//
#include <hip/hip_runtime.h>
#include <math.h>

#define NN 20000
#define EE 320000
#define DD 256
#define ETOT (EE + NN)

typedef __attribute__((ext_vector_type(8))) short bf8;
typedef __attribute__((ext_vector_type(4))) float f32x4;

__device__ __forceinline__ float gelu_exact(float x) {
    return 0.5f * x * (1.0f + erff(x * 0.70710678118654752f));
}

// round-to-nearest-even f32 -> bf16 bits
__device__ __forceinline__ unsigned short f2bf(float v) {
    unsigned u = __float_as_uint(v);
    u += 0x7fffu + ((u >> 16) & 1u);
    return (unsigned short)(u >> 16);
}
__device__ __forceinline__ float bf2f(unsigned short h) {
    return __uint_as_float(((unsigned)h) << 16);
}
__device__ __forceinline__ void split2(float v, unsigned short& hi, unsigned short& lo) {
    hi = f2bf(v);
    lo = f2bf(v - bf2f(hi));
}

// ---------------- row-normalize + hi/lo split: one wave per row ----------------
__global__ __launch_bounds__(256) void norm_k(const float* __restrict__ X,
                                              unsigned short* __restrict__ Xh,
                                              unsigned short* __restrict__ Xl) {
    int wave = (blockIdx.x * 256 + threadIdx.x) >> 6;
    int lane = threadIdx.x & 63;
    const float4 v = *(const float4*)&X[wave * DD + lane * 4];
    float ss = v.x * v.x + v.y * v.y + v.z * v.z + v.w * v.w;
    for (int off = 32; off > 0; off >>= 1) ss += __shfl_down(ss, off, 64);
    ss = __shfl(ss, 0, 64);
    float n = sqrtf(ss);
    if (n == 0.0f) n = 1e-8f;
    float inv = 1.0f / n;
    float o[4] = {v.x * inv, v.y * inv, v.z * inv, v.w * inv};
    ushort4 hv, lv;
    split2(o[0], hv.x, lv.x);
    split2(o[1], hv.y, lv.y);
    split2(o[2], hv.z, lv.z);
    split2(o[3], hv.w, lv.w);
    *(ushort4*)&Xh[wave * DD + lane * 4] = hv;
    *(ushort4*)&Xl[wave * DD + lane * 4] = lv;
}

// ---------------- W transpose + hi/lo split: Wt[n][k] = W[k][n] ----------------
__global__ __launch_bounds__(256) void splitw_k(const float* __restrict__ W,
                                                unsigned short* __restrict__ Wht,
                                                unsigned short* __restrict__ Wlt) {
    __shared__ float tile[64][65];
    int t = threadIdx.x;
    int k0 = blockIdx.x * 64;
    int c0 = blockIdx.y * 64;
#pragma unroll
    for (int i = 0; i < 16; ++i) {
        int idx = t + i * 256;
        int r = idx >> 6, c = idx & 63;
        tile[r][c] = W[(k0 + r) * DD + c0 + c];
    }
    __syncthreads();
#pragma unroll
    for (int i = 0; i < 16; ++i) {
        int idx = t + i * 256;
        int r = idx >> 6, c = idx & 63;
        float v = tile[c][r];
        unsigned short hi, lo;
        split2(v, hi, lo);
        Wht[(c0 + r) * DD + k0 + c] = hi;
        Wlt[(c0 + r) * DD + k0 + c] = lo;
    }
}

// ---------------- CSR build ----------------
__global__ void initdeg_k(int* deg) {
    int i = blockIdx.x * 256 + threadIdx.x;
    if (i < NN) deg[i] = 1;
}

__global__ void count_k(const int* __restrict__ ei, int* deg) {
    int e = blockIdx.x * 256 + threadIdx.x;
    if (e < EE) atomicAdd(&deg[ei[EE + e]], 1);
}

#define SCAN_T 1024
#define ITEMS 20
__global__ __launch_bounds__(SCAN_T) void scan_k(const int* __restrict__ deg, int* __restrict__ offs,
                                                 int* __restrict__ cursor) {
    __shared__ int part[SCAN_T];
    int t = threadIdx.x;
    int base = t * ITEMS;
    int local[ITEMS];
    int sum = 0;
#pragma unroll
    for (int i = 0; i < ITEMS; ++i) {
        int idx = base + i;
        int v = (idx < NN) ? deg[idx] : 0;
        local[i] = v;
        sum += v;
    }
    part[t] = sum;
    __syncthreads();
    for (int s = 1; s < SCAN_T; s <<= 1) {
        int v = (t >= s) ? part[t - s] : 0;
        __syncthreads();
        part[t] += v;
        __syncthreads();
    }
    int run = (t == 0) ? 0 : part[t - 1];
#pragma unroll
    for (int i = 0; i < ITEMS; ++i) {
        int idx = base + i;
        if (idx < NN) {
            offs[idx] = run;
            cursor[idx] = run;
            run += local[i];
        }
    }
    if (t == SCAN_T - 1) offs[NN] = part[SCAN_T - 1];
}

__global__ void fill_k(const int* __restrict__ ei, int* cursor, int* __restrict__ csr) {
    int e = blockIdx.x * 256 + threadIdx.x;
    if (e < EE) {
        int s = ei[e];
        int d = ei[EE + e];
        int p = atomicAdd(&cursor[d], 1);
        csr[p] = s;
    } else if (e < EE + NN) {
        int i = e - EE;
        int p = atomicAdd(&cursor[i], 1);
        csr[p] = i;
    }
}

// ---------------- MFMA GEMM: H[N,256] = (Xh+Xl) @ (Wht+Wlt)^T, 3-product split ----
// 64x128 tile, 256 threads / 4 waves; wave w owns rows [w*16, w*16+16).
// A fragments direct from global (line-coalesced, L2/LLC-resident);
// B hi/lo staged in LDS with register double-buffer prefetch.
#define LDB 40  // padded k-stride (bf16 elems): 80 B rows -> 2-way-only bank aliasing (free)
__global__ __launch_bounds__(256) void gemm_mfma(const unsigned short* __restrict__ Xh,
                                                 const unsigned short* __restrict__ Xl,
                                                 const unsigned short* __restrict__ Bh,
                                                 const unsigned short* __restrict__ Bl,
                                                 float* __restrict__ H) {
    __shared__ unsigned short sBh[128 * LDB], sBl[128 * LDB];
    int t = threadIdx.x;
    int m0 = blockIdx.x * 64;
    int n0 = blockIdx.y * 128;
    int w = t >> 6, l = t & 63;
    int rofs = l & 15, kch = l >> 4;

    f32x4 acc[8] = {};

    // B staging: each thread covers 2 chunks of 16 B per array per k-step
    int c1 = t, c2 = t + 256;
    int br1 = c1 >> 2, bo1 = (c1 & 3) * 8;
    int br2 = c2 >> 2, bo2 = (c2 & 3) * 8;
    const unsigned short* Bh1 = &Bh[(n0 + br1) * DD + bo1];
    const unsigned short* Bh2 = &Bh[(n0 + br2) * DD + bo2];
    const unsigned short* Bl1 = &Bl[(n0 + br1) * DD + bo1];
    const unsigned short* Bl2 = &Bl[(n0 + br2) * DD + bo2];
    bf8 rbh1 = *(const bf8*)Bh1;
    bf8 rbh2 = *(const bf8*)Bh2;
    bf8 rbl1 = *(const bf8*)Bl1;
    bf8 rbl2 = *(const bf8*)Bl2;

    // A fragment prefetch (16x16x32 A layout: row = lane&15, k = (lane>>4)*8 + j)
    int arow = m0 + w * 16 + rofs;
    bool aval = arow < NN;
    const unsigned short* Ahp = &Xh[(size_t)arow * DD + kch * 8];
    const unsigned short* Alp = &Xl[(size_t)arow * DD + kch * 8];
    bf8 zero = {0, 0, 0, 0, 0, 0, 0, 0};
    bf8 ah = aval ? *(const bf8*)Ahp : zero;
    bf8 al = aval ? *(const bf8*)Alp : zero;

    for (int k0 = 0; k0 < DD; k0 += 32) {
        if (k0) __syncthreads();
        *(bf8*)&sBh[br1 * LDB + bo1] = rbh1;
        *(bf8*)&sBh[br2 * LDB + bo2] = rbh2;
        *(bf8*)&sBl[br1 * LDB + bo1] = rbl1;
        *(bf8*)&sBl[br2 * LDB + bo2] = rbl2;
        __syncthreads();
        int kn = k0 + 32;
        bf8 nah = zero, nal = zero;
        if (kn < DD) {
            rbh1 = *(const bf8*)(Bh1 + kn);
            rbh2 = *(const bf8*)(Bh2 + kn);
            rbl1 = *(const bf8*)(Bl1 + kn);
            rbl2 = *(const bf8*)(Bl2 + kn);
            if (aval) {
                nah = *(const bf8*)(Ahp + kn);
                nal = *(const bf8*)(Alp + kn);
            }
        }
#pragma unroll
        for (int nt = 0; nt < 8; ++nt) {
            int r = nt * 16 + rofs;
            bf8 bh = *(const bf8*)&sBh[r * LDB + kch * 8];
            bf8 bl = *(const bf8*)&sBl[r * LDB + kch * 8];
            acc[nt] = __builtin_amdgcn_mfma_f32_16x16x32_bf16(ah, bh, acc[nt], 0, 0, 0);
            acc[nt] = __builtin_amdgcn_mfma_f32_16x16x32_bf16(ah, bl, acc[nt], 0, 0, 0);
            acc[nt] = __builtin_amdgcn_mfma_f32_16x16x32_bf16(al, bh, acc[nt], 0, 0, 0);
        }
        ah = nah;
        al = nal;
    }
    // C/D layout: col = lane&15, row = (lane>>4)*4 + reg  [m89]
    int row0 = m0 + w * 16 + (l >> 4) * 4;
    int colb = l & 15;
#pragma unroll
    for (int nt = 0; nt < 8; ++nt) {
        int cc = n0 + nt * 16 + colb;
#pragma unroll
        for (int r = 0; r < 4; ++r) {
            int row = row0 + r;
            if (row < NN) H[(size_t)row * DD + cc] = acc[nt][r];
        }
    }
}

// ---------------- s,d per node: one wave per row ----------------
__global__ __launch_bounds__(256) void sd_k(const float* __restrict__ H, const float* __restrict__ a_s,
                                            const float* __restrict__ a_d, float* __restrict__ sArr,
                                            float* __restrict__ dArr) {
    int wave = (blockIdx.x * 256 + threadIdx.x) >> 6;
    int lane = threadIdx.x & 63;
    const float4 h = *(const float4*)&H[wave * DD + lane * 4];
    const float4 vs = *(const float4*)&a_s[lane * 4];
    const float4 vd = *(const float4*)&a_d[lane * 4];
    float s = h.x * vs.x + h.y * vs.y + h.z * vs.z + h.w * vs.w;
    float d = h.x * vd.x + h.y * vd.y + h.z * vd.z + h.w * vd.w;
    for (int off = 32; off > 0; off >>= 1) {
        s += __shfl_down(s, off, 64);
        d += __shfl_down(d, off, 64);
    }
    if (lane == 0) {
        sArr[wave] = s;
        dArr[wave] = d;
    }
}

// ---------------- normalized edge weights: one wave per dst ----------------
__global__ __launch_bounds__(256) void wnorm_k(const float* __restrict__ sArr, const float* __restrict__ dArr,
                                               const int* __restrict__ offs, const int* __restrict__ csr,
                                               float* __restrict__ wn) {
    int dst = (blockIdx.x * 256 + threadIdx.x) >> 6;
    int lane = threadIdx.x & 63;
    int beg = offs[dst], end = offs[dst + 1];
    float dd = dArr[dst];
    float den = 0.0f;
    for (int base = beg; base < end; base += 64) {
        int idx = base + lane;
        float w = 0.0f;
        if (idx < end) {
            float a = sArr[csr[idx]] + dd;
            a = (a > 0.0f) ? a : 0.2f * a;
            w = expf(a);
            wn[idx] = w;
        }
        den += w;
    }
    for (int off = 32; off > 0; off >>= 1) den += __shfl_down(den, off, 64);
    den = __shfl(den, 0, 64);
    float inv = 1.0f / den;
    for (int base = beg; base < end; base += 64) {
        int idx = base + lane;
        if (idx < end) wn[idx] *= inv;
    }
}

// ---------------- strip SpMM + bias + gelu + hi/lo split ----------------
// grid (8, 625): blockIdx.x = 32-dim strip; XCD = linear%8 = blockIdx.x, so each
// XCD L2 holds one 2.5 MB H-strip. Edge loop unrolled 4x: 4 independent
// accumulator chains to cover L2 gather latency.
__global__ __launch_bounds__(256) void spmm_k(const float* __restrict__ H, const float* __restrict__ wn,
                                              const int* __restrict__ offs, const int* __restrict__ csr,
                                              const float* __restrict__ bias,
                                              unsigned short* __restrict__ Oh,
                                              unsigned short* __restrict__ Ol,
                                              float* __restrict__ outf32) {
    int t = threadIdx.x;
    int sub = t & 7;
    int dst = blockIdx.y * 32 + (t >> 3);
    int dim = blockIdx.x * 32 + sub * 4;

    int beg = offs[dst], end = offs[dst + 1];
    const float* Hs = H + dim;

    float4 A0 = make_float4(0, 0, 0, 0), A1 = A0, A2 = A0, A3 = A0;

    int e = beg;
    for (; e + 3 < end; e += 4) {
        int s0 = csr[e], s1 = csr[e + 1], s2 = csr[e + 2], s3 = csr[e + 3];
        float w0 = wn[e], w1 = wn[e + 1], w2 = wn[e + 2], w3 = wn[e + 3];
        const float4 h0 = *(const float4*)&Hs[(size_t)s0 * DD];
        const float4 h1 = *(const float4*)&Hs[(size_t)s1 * DD];
        const float4 h2 = *(const float4*)&Hs[(size_t)s2 * DD];
        const float4 h3 = *(const float4*)&Hs[(size_t)s3 * DD];
        A0.x += w0 * h0.x; A0.y += w0 * h0.y; A0.z += w0 * h0.z; A0.w += w0 * h0.w;
        A1.x += w1 * h1.x; A1.y += w1 * h1.y; A1.z += w1 * h1.z; A1.w += w1 * h1.w;
        A2.x += w2 * h2.x; A2.y += w2 * h2.y; A2.z += w2 * h2.z; A2.w += w2 * h2.w;
        A3.x += w3 * h3.x; A3.y += w3 * h3.y; A3.z += w3 * h3.z; A3.w += w3 * h3.w;
    }
    for (; e < end; ++e) {
        int s0 = csr[e];
        float w0 = wn[e];
        const float4 h0 = *(const float4*)&Hs[(size_t)s0 * DD];
        A0.x += w0 * h0.x; A0.y += w0 * h0.y; A0.z += w0 * h0.z; A0.w += w0 * h0.w;
    }

    const float4 b = *(const float4*)&bias[dim];
    float o0 = gelu_exact(A0.x + A1.x + A2.x + A3.x + b.x);
    float o1 = gelu_exact(A0.y + A1.y + A2.y + A3.y + b.y);
    float o2 = gelu_exact(A0.z + A1.z + A2.z + A3.z + b.z);
    float o3 = gelu_exact(A0.w + A1.w + A2.w + A3.w + b.w);

    ushort4 hv, lv;
    split2(o0, hv.x, lv.x);
    split2(o1, hv.y, lv.y);
    split2(o2, hv.z, lv.z);
    split2(o3, hv.w, lv.w);
    *(ushort4*)&Oh[dst * DD + dim] = hv;
    *(ushort4*)&Ol[dst * DD + dim] = lv;
    if (outf32) {
        float4 o = make_float4(o0, o1, o2, o3);
        *(float4*)&outf32[dst * DD + dim] = o;
    }
}

extern "C" void kernel_launch(void* const* d_in, const int* in_sizes, int n_in,
                              void* d_out, int out_size, void* d_ws, size_t ws_size,
                              hipStream_t stream) {
    const float* x  = (const float*)d_in[0];
    const int* ei   = (const int*)d_in[1];
    const float* W1 = (const float*)d_in[4];
    const float* as1 = (const float*)d_in[5];
    const float* ad1 = (const float*)d_in[6];
    const float* b1 = (const float*)d_in[7];
    const float* W2 = (const float*)d_in[8];
    const float* as2 = (const float*)d_in[9];
    const float* ad2 = (const float*)d_in[10];
    const float* b2 = (const float*)d_in[11];
    const float* W3 = (const float*)d_in[12];
    const float* as3 = (const float*)d_in[13];
    const float* ad3 = (const float*)d_in[14];
    const float* b3 = (const float*)d_in[15];

    float* H = (float*)d_ws;                              // [N,256] f32
    unsigned short* Xh = (unsigned short*)(H + (size_t)NN * DD);  // [N,256] bf16 bits
    unsigned short* Xl = Xh + (size_t)NN * DD;
    unsigned short* Wht1 = Xl + (size_t)NN * DD;          // 6 x [256,256]
    unsigned short* Wlt1 = Wht1 + DD * DD;
    unsigned short* Wht2 = Wlt1 + DD * DD;
    unsigned short* Wlt2 = Wht2 + DD * DD;
    unsigned short* Wht3 = Wlt2 + DD * DD;
    unsigned short* Wlt3 = Wht3 + DD * DD;
    float* sArr = (float*)(Wlt3 + DD * DD);               // [N]
    float* dArr = sArr + NN;                              // [N]
    int* offs = (int*)(dArr + NN);                        // [N+1]
    int* cursor = offs + (NN + 1);                        // [N]
    int* csr = cursor + NN;                               // [ETOT]
    int* deg = csr + ETOT;                                // [N]
    float* wn = (float*)(deg + NN);                       // [ETOT]

    // ---- build CSR (by dst) ----
    initdeg_k<<<(NN + 255) / 256, 256, 0, stream>>>(deg);
    count_k<<<(EE + 255) / 256, 256, 0, stream>>>(ei, deg);
    scan_k<<<1, SCAN_T, 0, stream>>>(deg, offs, cursor);
    fill_k<<<(ETOT + 255) / 256, 256, 0, stream>>>(ei, cursor, csr);

    // ---- W transpose+split (once each) ----
    dim3 wgrid(4, 4);
    splitw_k<<<wgrid, 256, 0, stream>>>(W1, Wht1, Wlt1);
    splitw_k<<<wgrid, 256, 0, stream>>>(W2, Wht2, Wlt2);
    splitw_k<<<wgrid, 256, 0, stream>>>(W3, Wht3, Wlt3);

    // ---- normalize input rows -> Xh/Xl ----
    norm_k<<<NN / 4, 256, 0, stream>>>(x, Xh, Xl);

    dim3 ggrid((NN + 63) / 64, DD / 128);
    dim3 sgrid(DD / 32, NN / 32);  // x = strip (XCD pin), y = dst group

    // layer 1
    gemm_mfma<<<ggrid, 256, 0, stream>>>(Xh, Xl, Wht1, Wlt1, H);
    sd_k<<<NN / 4, 256, 0, stream>>>(H, as1, ad1, sArr, dArr);
    wnorm_k<<<NN / 4, 256, 0, stream>>>(sArr, dArr, offs, csr, wn);
    spmm_k<<<sgrid, 256, 0, stream>>>(H, wn, offs, csr, b1, Xh, Xl, nullptr);

    // layer 2
    gemm_mfma<<<ggrid, 256, 0, stream>>>(Xh, Xl, Wht2, Wlt2, H);
    sd_k<<<NN / 4, 256, 0, stream>>>(H, as2, ad2, sArr, dArr);
    wnorm_k<<<NN / 4, 256, 0, stream>>>(sArr, dArr, offs, csr, wn);
    spmm_k<<<sgrid, 256, 0, stream>>>(H, wn, offs, csr, b2, Xh, Xl, nullptr);

    // layer 3
    gemm_mfma<<<ggrid, 256, 0, stream>>>(Xh, Xl, Wht3, Wlt3, H);
    sd_k<<<NN / 4, 256, 0, stream>>>(H, as3, ad3, sArr, dArr);
    wnorm_k<<<NN / 4, 256, 0, stream>>>(sArr, dArr, offs, csr, wn);
    spmm_k<<<sgrid, 256, 0, stream>>>(H, wn, offs, csr, b3, Xh, Xl, (float*)d_out);
}

// Round 5
// 340.788 us; speedup vs baseline: 1.3542x; 1.0887x over previous
//
#include <hip/hip_runtime.h>
#include <math.h>

#define NN 20000
#define EE 320000
#define DD 256
#define ETOT (EE + NN)
#define EDGE_CAP 1536  // max edges per 32-dst group (mean 544, +40 sigma safe)

typedef __attribute__((ext_vector_type(8))) short bf8;
typedef __attribute__((ext_vector_type(4))) float f32x4;

__device__ __forceinline__ float gelu_exact(float x) {
    return 0.5f * x * (1.0f + erff(x * 0.70710678118654752f));
}

// round-to-nearest-even f32 -> bf16 bits
__device__ __forceinline__ unsigned short f2bf(float v) {
    unsigned u = __float_as_uint(v);
    u += 0x7fffu + ((u >> 16) & 1u);
    return (unsigned short)(u >> 16);
}
__device__ __forceinline__ float bf2f(unsigned short h) {
    return __uint_as_float(((unsigned)h) << 16);
}
__device__ __forceinline__ void split2(float v, unsigned short& hi, unsigned short& lo) {
    hi = f2bf(v);
    lo = f2bf(v - bf2f(hi));
}

// ---------------- row-normalize + split X; zero s/d buffers; init deg ----------------
__global__ __launch_bounds__(256) void norm_k(const float* __restrict__ X,
                                              unsigned short* __restrict__ Xh,
                                              unsigned short* __restrict__ Xl,
                                              float* __restrict__ sdZero,  // 6*NN floats
                                              int* __restrict__ deg) {
    int t = threadIdx.x;
    int bid = blockIdx.x;  // 0..4999
    // side duties: zero 24 floats of s/d buffers, init 4 deg entries to 1 (self loop)
    if (t < 24) sdZero[bid * 24 + t] = 0.0f;
    if (t >= 32 && t < 36) deg[bid * 4 + (t - 32)] = 1;

    int wave = (bid * 256 + t) >> 6;
    int lane = t & 63;
    const float4 v = *(const float4*)&X[wave * DD + lane * 4];
    float ss = v.x * v.x + v.y * v.y + v.z * v.z + v.w * v.w;
    for (int off = 32; off > 0; off >>= 1) ss += __shfl_down(ss, off, 64);
    ss = __shfl(ss, 0, 64);
    float n = sqrtf(ss);
    if (n == 0.0f) n = 1e-8f;
    float inv = 1.0f / n;
    float o[4] = {v.x * inv, v.y * inv, v.z * inv, v.w * inv};
    ushort4 hv, lv;
    split2(o[0], hv.x, lv.x);
    split2(o[1], hv.y, lv.y);
    split2(o[2], hv.z, lv.z);
    split2(o[3], hv.w, lv.w);
    *(ushort4*)&Xh[wave * DD + lane * 4] = hv;
    *(ushort4*)&Xl[wave * DD + lane * 4] = lv;
}

// ---------------- W transpose + hi/lo split for all 3 layers (z = layer) ----------------
__global__ __launch_bounds__(256) void splitw_k(const float* __restrict__ W1, const float* __restrict__ W2,
                                                const float* __restrict__ W3, unsigned short* __restrict__ Whl) {
    __shared__ float tile[64][65];
    int t = threadIdx.x;
    int k0 = blockIdx.x * 64;
    int c0 = blockIdx.y * 64;
    int z = blockIdx.z;
    const float* W = (z == 0) ? W1 : (z == 1) ? W2 : W3;
    unsigned short* Wht = Whl + (size_t)z * 2 * DD * DD;
    unsigned short* Wlt = Wht + DD * DD;
#pragma unroll
    for (int i = 0; i < 16; ++i) {
        int idx = t + i * 256;
        int r = idx >> 6, c = idx & 63;
        tile[r][c] = W[(k0 + r) * DD + c0 + c];
    }
    __syncthreads();
#pragma unroll
    for (int i = 0; i < 16; ++i) {
        int idx = t + i * 256;
        int r = idx >> 6, c = idx & 63;
        float v = tile[c][r];
        unsigned short hi, lo;
        split2(v, hi, lo);
        Wht[(c0 + r) * DD + k0 + c] = hi;
        Wlt[(c0 + r) * DD + k0 + c] = lo;
    }
}

// ---------------- CSR build ----------------
__global__ void count_k(const int* __restrict__ ei, int* deg) {
    int e = blockIdx.x * 256 + threadIdx.x;
    if (e < EE) atomicAdd(&deg[ei[EE + e]], 1);
}

#define SCAN_T 1024
#define ITEMS 20
__global__ __launch_bounds__(SCAN_T) void scan_k(const int* __restrict__ deg, int* __restrict__ offs,
                                                 int* __restrict__ cursor, int* __restrict__ csr) {
    __shared__ int part[SCAN_T];
    int t = threadIdx.x;
    int base = t * ITEMS;
    int local[ITEMS];
    int sum = 0;
#pragma unroll
    for (int i = 0; i < ITEMS; ++i) {
        int idx = base + i;
        int v = (idx < NN) ? deg[idx] : 0;
        local[i] = v;
        sum += v;
    }
    part[t] = sum;
    __syncthreads();
    for (int s = 1; s < SCAN_T; s <<= 1) {
        int v = (t >= s) ? part[t - s] : 0;
        __syncthreads();
        part[t] += v;
        __syncthreads();
    }
    int run = (t == 0) ? 0 : part[t - 1];
#pragma unroll
    for (int i = 0; i < ITEMS; ++i) {
        int idx = base + i;
        if (idx < NN) {
            offs[idx] = run;
            cursor[idx] = run + 1;  // slot 0 of segment = self loop
            csr[run] = idx;
            run += local[i];
        }
    }
    if (t == SCAN_T - 1) offs[NN] = part[SCAN_T - 1];
}

__global__ void fill_k(const int* __restrict__ ei, int* cursor, int* __restrict__ csr) {
    int e = blockIdx.x * 256 + threadIdx.x;
    if (e < EE) {
        int s = ei[e];
        int d = ei[EE + e];
        int p = atomicAdd(&cursor[d], 1);
        csr[p] = s;
    }
}

// ---------------- MFMA GEMM + fused s,d epilogue ----------------
// 64x128 tile, 4 waves; A fragments direct from global; B staged in LDS w/ reg dbuf.
#define LDB 40
__global__ __launch_bounds__(256) void gemm_sd(const unsigned short* __restrict__ Xh,
                                               const unsigned short* __restrict__ Xl,
                                               const unsigned short* __restrict__ Bh,
                                               const unsigned short* __restrict__ Bl,
                                               const float* __restrict__ a_s,
                                               const float* __restrict__ a_d,
                                               float* __restrict__ H,
                                               float* __restrict__ sArr,
                                               float* __restrict__ dArr) {
    __shared__ unsigned short sBh[128 * LDB], sBl[128 * LDB];
    int t = threadIdx.x;
    int m0 = blockIdx.x * 64;
    int n0 = blockIdx.y * 128;
    int w = t >> 6, l = t & 63;
    int rofs = l & 15, kch = l >> 4;

    f32x4 acc[8] = {};

    int c1 = t, c2 = t + 256;
    int br1 = c1 >> 2, bo1 = (c1 & 3) * 8;
    int br2 = c2 >> 2, bo2 = (c2 & 3) * 8;
    const unsigned short* Bh1 = &Bh[(n0 + br1) * DD + bo1];
    const unsigned short* Bh2 = &Bh[(n0 + br2) * DD + bo2];
    const unsigned short* Bl1 = &Bl[(n0 + br1) * DD + bo1];
    const unsigned short* Bl2 = &Bl[(n0 + br2) * DD + bo2];
    bf8 rbh1 = *(const bf8*)Bh1;
    bf8 rbh2 = *(const bf8*)Bh2;
    bf8 rbl1 = *(const bf8*)Bl1;
    bf8 rbl2 = *(const bf8*)Bl2;

    int arow = m0 + w * 16 + rofs;
    bool aval = arow < NN;
    const unsigned short* Ahp = &Xh[(size_t)arow * DD + kch * 8];
    const unsigned short* Alp = &Xl[(size_t)arow * DD + kch * 8];
    bf8 zero = {0, 0, 0, 0, 0, 0, 0, 0};
    bf8 ah = aval ? *(const bf8*)Ahp : zero;
    bf8 al = aval ? *(const bf8*)Alp : zero;

    for (int k0 = 0; k0 < DD; k0 += 32) {
        if (k0) __syncthreads();
        *(bf8*)&sBh[br1 * LDB + bo1] = rbh1;
        *(bf8*)&sBh[br2 * LDB + bo2] = rbh2;
        *(bf8*)&sBl[br1 * LDB + bo1] = rbl1;
        *(bf8*)&sBl[br2 * LDB + bo2] = rbl2;
        __syncthreads();
        int kn = k0 + 32;
        bf8 nah = zero, nal = zero;
        if (kn < DD) {
            rbh1 = *(const bf8*)(Bh1 + kn);
            rbh2 = *(const bf8*)(Bh2 + kn);
            rbl1 = *(const bf8*)(Bl1 + kn);
            rbl2 = *(const bf8*)(Bl2 + kn);
            if (aval) {
                nah = *(const bf8*)(Ahp + kn);
                nal = *(const bf8*)(Alp + kn);
            }
        }
#pragma unroll
        for (int nt = 0; nt < 8; ++nt) {
            int r = nt * 16 + rofs;
            bf8 bh = *(const bf8*)&sBh[r * LDB + kch * 8];
            bf8 bl = *(const bf8*)&sBl[r * LDB + kch * 8];
            acc[nt] = __builtin_amdgcn_mfma_f32_16x16x32_bf16(ah, bh, acc[nt], 0, 0, 0);
            acc[nt] = __builtin_amdgcn_mfma_f32_16x16x32_bf16(ah, bl, acc[nt], 0, 0, 0);
            acc[nt] = __builtin_amdgcn_mfma_f32_16x16x32_bf16(al, bh, acc[nt], 0, 0, 0);
        }
        ah = nah;
        al = nal;
    }
    // C/D layout: col = lane&15, row = (lane>>4)*4 + reg  [m89]
    int row0 = m0 + w * 16 + (l >> 4) * 4;
    int colb = l & 15;
    float sp[4] = {0, 0, 0, 0}, dp[4] = {0, 0, 0, 0};
#pragma unroll
    for (int nt = 0; nt < 8; ++nt) {
        int cc = n0 + nt * 16 + colb;
        float vas = a_s[cc], vad = a_d[cc];
#pragma unroll
        for (int r = 0; r < 4; ++r) {
            int row = row0 + r;
            if (row < NN) H[(size_t)row * DD + cc] = acc[nt][r];
            sp[r] += acc[nt][r] * vas;
            dp[r] += acc[nt][r] * vad;
        }
    }
#pragma unroll
    for (int m = 1; m < 16; m <<= 1) {
#pragma unroll
        for (int r = 0; r < 4; ++r) {
            sp[r] += __shfl_xor(sp[r], m, 64);
            dp[r] += __shfl_xor(dp[r], m, 64);
        }
    }
    if (colb == 0) {
#pragma unroll
        for (int r = 0; r < 4; ++r) {
            int row = row0 + r;
            if (row < NN) {
                atomicAdd(&sArr[row], sp[r]);
                atomicAdd(&dArr[row], dp[r]);
            }
        }
    }
}

// ---------------- fused softmax-weights + strip SpMM + bias + gelu + split ----------------
// grid (8, 625): blockIdx.x = 32-dim strip (XCD pin: linear%8=strip); 32 dsts/block,
// 8 threads/dst. Pass 1: exp weights+src into LDS, shfl den-reduce, normalize.
// Pass 2: unroll-4 gather of H rows (strip L2-resident).
__global__ __launch_bounds__(256) void spmm_k(const float* __restrict__ H, const float* __restrict__ sArr,
                                              const float* __restrict__ dArr, const int* __restrict__ offs,
                                              const int* __restrict__ csr, const float* __restrict__ bias,
                                              unsigned short* __restrict__ Oh,
                                              unsigned short* __restrict__ Ol,
                                              float* __restrict__ outf32) {
    __shared__ float wLds[EDGE_CAP];
    __shared__ int sLds[EDGE_CAP];
    int t = threadIdx.x;
    int sub = t & 7;
    int g = t >> 3;
    int dst0 = blockIdx.y * 32;
    int dst = dst0 + g;
    int dim = blockIdx.x * 32 + sub * 4;

    int blkBeg = offs[dst0];
    int beg = offs[dst], end = offs[dst + 1];
    float dd = dArr[dst];

    // pass 1: weights
    float den = 0.0f;
    for (int e = beg + sub; e < end; e += 8) {
        int s = csr[e];
        float a = sArr[s] + dd;
        a = (a > 0.0f) ? a : 0.2f * a;
        float wv = expf(a);
        wLds[e - blkBeg] = wv;
        sLds[e - blkBeg] = s;
        den += wv;
    }
    den += __shfl_xor(den, 1, 64);
    den += __shfl_xor(den, 2, 64);
    den += __shfl_xor(den, 4, 64);
    float inv = 1.0f / den;
    for (int e = beg + sub; e < end; e += 8) wLds[e - blkBeg] *= inv;
    __syncthreads();

    // pass 2: gather
    const float* Hs = H + dim;
    float4 A0 = make_float4(0, 0, 0, 0), A1 = A0, A2 = A0, A3 = A0;
    int e = beg - blkBeg, lend = end - blkBeg;
    for (; e + 3 < lend; e += 4) {
        int s0 = sLds[e], s1 = sLds[e + 1], s2 = sLds[e + 2], s3 = sLds[e + 3];
        float w0 = wLds[e], w1 = wLds[e + 1], w2 = wLds[e + 2], w3 = wLds[e + 3];
        const float4 h0 = *(const float4*)&Hs[(size_t)s0 * DD];
        const float4 h1 = *(const float4*)&Hs[(size_t)s1 * DD];
        const float4 h2 = *(const float4*)&Hs[(size_t)s2 * DD];
        const float4 h3 = *(const float4*)&Hs[(size_t)s3 * DD];
        A0.x += w0 * h0.x; A0.y += w0 * h0.y; A0.z += w0 * h0.z; A0.w += w0 * h0.w;
        A1.x += w1 * h1.x; A1.y += w1 * h1.y; A1.z += w1 * h1.z; A1.w += w1 * h1.w;
        A2.x += w2 * h2.x; A2.y += w2 * h2.y; A2.z += w2 * h2.z; A2.w += w2 * h2.w;
        A3.x += w3 * h3.x; A3.y += w3 * h3.y; A3.z += w3 * h3.z; A3.w += w3 * h3.w;
    }
    for (; e < lend; ++e) {
        int s0 = sLds[e];
        float w0 = wLds[e];
        const float4 h0 = *(const float4*)&Hs[(size_t)s0 * DD];
        A0.x += w0 * h0.x; A0.y += w0 * h0.y; A0.z += w0 * h0.z; A0.w += w0 * h0.w;
    }

    const float4 b = *(const float4*)&bias[dim];
    float o0 = gelu_exact(A0.x + A1.x + A2.x + A3.x + b.x);
    float o1 = gelu_exact(A0.y + A1.y + A2.y + A3.y + b.y);
    float o2 = gelu_exact(A0.z + A1.z + A2.z + A3.z + b.z);
    float o3 = gelu_exact(A0.w + A1.w + A2.w + A3.w + b.w);

    ushort4 hv, lv;
    split2(o0, hv.x, lv.x);
    split2(o1, hv.y, lv.y);
    split2(o2, hv.z, lv.z);
    split2(o3, hv.w, lv.w);
    *(ushort4*)&Oh[dst * DD + dim] = hv;
    *(ushort4*)&Ol[dst * DD + dim] = lv;
    if (outf32) {
        float4 o = make_float4(o0, o1, o2, o3);
        *(float4*)&outf32[dst * DD + dim] = o;
    }
}

extern "C" void kernel_launch(void* const* d_in, const int* in_sizes, int n_in,
                              void* d_out, int out_size, void* d_ws, size_t ws_size,
                              hipStream_t stream) {
    const float* x  = (const float*)d_in[0];
    const int* ei   = (const int*)d_in[1];
    const float* W1 = (const float*)d_in[4];
    const float* as1 = (const float*)d_in[5];
    const float* ad1 = (const float*)d_in[6];
    const float* b1 = (const float*)d_in[7];
    const float* W2 = (const float*)d_in[8];
    const float* as2 = (const float*)d_in[9];
    const float* ad2 = (const float*)d_in[10];
    const float* b2 = (const float*)d_in[11];
    const float* W3 = (const float*)d_in[12];
    const float* as3 = (const float*)d_in[13];
    const float* ad3 = (const float*)d_in[14];
    const float* b3 = (const float*)d_in[15];

    float* H = (float*)d_ws;                                      // [N,256] f32
    unsigned short* Xh = (unsigned short*)(H + (size_t)NN * DD);  // [N,256] bf16
    unsigned short* Xl = Xh + (size_t)NN * DD;
    unsigned short* Whl = Xl + (size_t)NN * DD;                   // 6 x [256,256]
    float* sd = (float*)(Whl + (size_t)6 * DD * DD);              // 6*NN: s1,d1,s2,d2,s3,d3
    int* offs = (int*)(sd + (size_t)6 * NN);                      // [N+1]
    int* cursor = offs + (NN + 1);                                // [N]
    int* csr = cursor + NN;                                       // [ETOT]
    int* deg = csr + ETOT;                                        // [N]

    float* sA1 = sd,           *dA1 = sd + NN;
    float* sA2 = sd + 2 * NN,  *dA2 = sd + 3 * NN;
    float* sA3 = sd + 4 * NN,  *dA3 = sd + 5 * NN;
    unsigned short* Wt1 = Whl;
    unsigned short* Wt2 = Whl + (size_t)2 * DD * DD;
    unsigned short* Wt3 = Whl + (size_t)4 * DD * DD;

    // 1: normalize+split X, zero s/d, init deg
    norm_k<<<NN / 4, 256, 0, stream>>>(x, Xh, Xl, sd, deg);
    // 2-4: CSR build
    count_k<<<(EE + 255) / 256, 256, 0, stream>>>(ei, deg);
    scan_k<<<1, SCAN_T, 0, stream>>>(deg, offs, cursor, csr);
    fill_k<<<(EE + 255) / 256, 256, 0, stream>>>(ei, cursor, csr);
    // 5: all W transposes+splits
    splitw_k<<<dim3(4, 4, 3), 256, 0, stream>>>(W1, W2, W3, Whl);

    dim3 ggrid((NN + 63) / 64, DD / 128);
    dim3 sgrid(DD / 32, NN / 32);

    // layer 1
    gemm_sd<<<ggrid, 256, 0, stream>>>(Xh, Xl, Wt1, Wt1 + DD * DD, as1, ad1, H, sA1, dA1);
    spmm_k<<<sgrid, 256, 0, stream>>>(H, sA1, dA1, offs, csr, b1, Xh, Xl, nullptr);
    // layer 2
    gemm_sd<<<ggrid, 256, 0, stream>>>(Xh, Xl, Wt2, Wt2 + DD * DD, as2, ad2, H, sA2, dA2);
    spmm_k<<<sgrid, 256, 0, stream>>>(H, sA2, dA2, offs, csr, b2, Xh, Xl, nullptr);
    // layer 3
    gemm_sd<<<ggrid, 256, 0, stream>>>(Xh, Xl, Wt3, Wt3 + DD * DD, as3, ad3, H, sA3, dA3);
    spmm_k<<<sgrid, 256, 0, stream>>>(H, sA3, dA3, offs, csr, b3, Xh, Xl, (float*)d_out);
}